// Round 2
// baseline (276.960 us; speedup 1.0000x reference)
//
#include <hip/hip_runtime.h>

// Mandelbrot counts — R6-proven bit-exact arithmetic + compaction + wave-
// aggregated enqueue (R8) + per-lane work refill in stage B (R10).
//
// R9 post-mortem: ballot early-exit was NEUTRAL because the input is
// uniform-RANDOM c per pixel (no spatial coherence). A wave exits only when
// all 64 random lanes are dead: P ~ 0.82^64 ~ 3e-6 in stage B -> exit never
// fires; every wave runs ~240 iters (max-of-64). Stage B issues ~460M
// lane-iterations, only ~153M live (in-set 0.35M x 240 = 84M; escaper decay
// ~K/t integrates to ~69M).
//
// R10: make it sum-of-live instead of max-of-64. Stage B = persistent waves;
// each lane owns one record; every 12 checks, lanes that retired (escaped or
// done==240) write out and are refilled from the segment queue via ONE
// leader atomicAdd on a per-segment cursor (64 cursors, 64B apart — same
// proven striping as stage A; ~210k refills / 64 addrs, overlapped).
// Exactness: cnt is frozen once act==0 (sticky), and 240 = 20 chunks of 12,
// so every record executes checks z_16..z_255 or retires dead — identical
// values to the fixed-trip version (absmax=0 lineage).
// Stage A reverted to exact R8 body (R9's ballots were pure overhead).
//
// Proven iter body (absmax=0 in R6/R7/R8/R9), pinned with inline asm:
//   zi2 = fl32(zi*zi); mag = fma(zr,zr,zi2)
//   nr  = fl32(fma(zr,zr,-zi2) + cr); zi' = fma(2*zr, zi, ci)
// Cardioid/bulb shortcut margin 1e-3 (HW-validated, absmax=0).
//
// d_ws: [0,4096) 64 lines of 64B: {enq counter @+0, read cursor @+4} | q1:
// float4 recs, seg-major (seg*seg_cap+slot) | q2: int idx. Segment overflow
// -> finish inline (correct, slower). Tiny ws -> monolithic fallback.

#define MAX_ITERS 256

__device__ __forceinline__ float mul32(float a, float b) {
    float d; asm("v_mul_f32 %0, %1, %2" : "=v"(d) : "v"(a), "v"(b)); return d;
}
__device__ __forceinline__ float add32(float a, float b) {
    float d; asm("v_add_f32 %0, %1, %2" : "=v"(d) : "v"(a), "v"(b)); return d;
}
__device__ __forceinline__ float fma32(float a, float b, float c) {
    float d; asm("v_fma_f32 %0, %1, %2, %3" : "=v"(d) : "v"(a), "v"(b), "v"(c)); return d;
}
__device__ __forceinline__ float fma32_negc(float a, float b, float c) {
    float d; asm("v_fma_f32 %0, %1, %2, -%3" : "=v"(d) : "v"(a), "v"(b), "v"(c)); return d;
}

__device__ __forceinline__ void iter_checks(float cr, float ci,
                                            float& zr, float& zi,
                                            float& act, float& cnt, int nchecks)
{
    #pragma unroll 8
    for (int s = 0; s < nchecks; ++s) {
        const float zi2 = mul32(zi, zi);
        const float mag = fma32(zr, zr, zi2);
        act = (mag < 4.0f) ? act : 0.0f;      // sticky escape, NaN-safe
        cnt = cnt + act;                      // exact small-int add
        const float t   = fma32_negc(zr, zr, zi2);
        const float nr  = add32(t, cr);
        const float t2  = add32(zr, zr);
        zi = fma32(t2, zi, ci);
        zr = nr;
    }
}

__global__ void zero_ctrs(unsigned char* ws) {
    // zero both the enqueue counter (+0) and the read cursor (+4) per segment
    if (threadIdx.x < 128)
        *(unsigned*)(ws + (size_t)(threadIdx.x >> 1) * 64u
                        + (size_t)(threadIdx.x & 1) * 4u) = 0u;
}

__global__ __launch_bounds__(256) void mandel_stage_a(
    const float* __restrict__ c_real, const float* __restrict__ c_imag,
    float* __restrict__ out, unsigned char* __restrict__ ws,
    unsigned seg_cap, int n)
{
    int i = blockIdx.x * blockDim.x + threadIdx.x;
    if (i >= n) return;
    const float cr = c_real[i];
    const float ci = c_imag[i];

    // Closed-form safe-interior shortcut (margin absorbs any rounding).
    const float xq = cr - 0.25f;
    const float q  = xq * xq + ci * ci;
    const bool in_card = (q * (q + xq) - 0.25f * ci * ci) < -1e-3f;
    const float xb = cr + 1.0f;
    const bool in_bulb = (xb * xb + ci * ci) < (0.0625f - 1e-3f);
    const bool shortcut = in_card | in_bulb;

    float zr = cr, zi = ci, act = 1.0f, cnt = 0.0f;
    iter_checks(cr, ci, zr, zi, act, cnt, 16);   // checks z_0..z_15

    const bool surv = (!shortcut) && (act != 0.0f);

    // Wave-aggregated enqueue: one atomic per wave, striped over 64 counters.
    const unsigned long long m = __ballot(surv);
    if (m != 0ull) {
        const int lane = __builtin_amdgcn_mbcnt_hi(
            ~0u, __builtin_amdgcn_mbcnt_lo(~0u, 0));
        const int leader = (int)__ffsll((unsigned long long)m) - 1;
        const int seg = blockIdx.x & 63;
        unsigned* ctr = (unsigned*)(ws + (size_t)seg * 64u);
        unsigned base = 0u;
        if (lane == leader) base = atomicAdd(ctr, (unsigned)__popcll(m));
        base = (unsigned)__shfl((int)base, leader, 64);
        if (surv) {
            const unsigned rank = (unsigned)__popcll(m & ((1ull << lane) - 1ull));
            const unsigned slot = base + rank;
            if (slot < seg_cap) {
                float4* q1 = (float4*)(ws + 4096);
                int*    q2 = (int*)(ws + 4096 + (size_t)seg_cap * 64u * 16u);
                const size_t p = (size_t)seg * seg_cap + slot;
                q1[p] = make_float4(zr, zi, cr, ci);
                q2[p] = i;
                return;
            }
            iter_checks(cr, ci, zr, zi, act, cnt, 240);  // overflow: inline
            out[i] = cnt;
            return;
        }
    }
    out[i] = shortcut ? 256.0f : cnt;
}

// Stage B (R10): persistent waves, per-lane record refill. Each lane owns one
// record; every CHUNK=12 checks, retired lanes (escaped or done==240) write
// out[idx] and the wave refills them with one leader atomicAdd on the
// per-segment read cursor. Lane utilization ~90% vs ~33% for max-of-64.
__global__ __launch_bounds__(256) void mandel_stage_b(
    float* __restrict__ out, unsigned char* __restrict__ ws,
    unsigned seg_cap)
{
    const int seg = (int)(blockIdx.x & 63u);
    const unsigned cnt_s = *(const unsigned*)(ws + (size_t)seg * 64u);
    const unsigned nq = (cnt_s < seg_cap) ? cnt_s : seg_cap;
    const float4* q1 = (const float4*)(ws + 4096);
    const int*    q2 = (const int*)(ws + 4096 + (size_t)seg_cap * 64u * 16u);
    unsigned* cursor = (unsigned*)(ws + (size_t)seg * 64u + 4u);

    const int lane = __builtin_amdgcn_mbcnt_hi(
        ~0u, __builtin_amdgcn_mbcnt_lo(~0u, 0));

    float zr = 0.0f, zi = 0.0f, cr = 0.0f, ci = 0.0f, act = 0.0f, cnt = 0.0f;
    int idx = 0, done = 0;
    bool have = false;
    bool q_empty = (nq == 0u);

    for (;;) {
        // Retire finished lanes: escaped (cnt frozen) or all 240 checks done.
        if (have && (act == 0.0f || done >= 240)) {
            out[idx] = cnt;
            have = false;
        }
        const unsigned long long need_m = __ballot(!have);
        if (!q_empty && need_m != 0ull) {         // wave-uniform condition
            const int leader = (int)__ffsll(need_m) - 1;
            unsigned base = 0u;
            if (lane == leader)
                base = atomicAdd(cursor, (unsigned)__popcll(need_m));
            base = (unsigned)__shfl((int)base, leader, 64);
            if (base >= nq) q_empty = true;       // stop future atomics
            if (!have) {
                const unsigned slot = base +
                    (unsigned)__popcll(need_m & ((1ull << lane) - 1ull));
                if (slot < nq) {
                    const size_t p = (size_t)seg * seg_cap + slot;
                    const float4 rec = q1[p];
                    idx = q2[p];
                    zr = rec.x; zi = rec.y; cr = rec.z; ci = rec.w;
                    act = 1.0f; cnt = 16.0f; done = 0;
                    have = true;
                }
            }
        }
        if (__ballot(have) == 0ull) break;
        // Lanes without a record run garbage arithmetic here — harmless
        // (no traps, their out was already written, ballot gates the loop).
        iter_checks(cr, ci, zr, zi, act, cnt, 12);   // 240 = 20 chunks of 12
        done += 12;
    }
}

// Fallback: the R6-proven monolithic kernel (used only if d_ws is tiny).
__global__ __launch_bounds__(256) void mandel_mono(
    const float* __restrict__ c_real, const float* __restrict__ c_imag,
    float* __restrict__ out, int n)
{
    int i = blockIdx.x * blockDim.x + threadIdx.x;
    if (i >= n) return;
    const float cr = c_real[i], ci = c_imag[i];
    float zr = cr, zi = ci, act = 1.0f, cnt = 0.0f;
    iter_checks(cr, ci, zr, zi, act, cnt, MAX_ITERS);
    out[i] = cnt;
}

extern "C" void kernel_launch(void* const* d_in, const int* in_sizes, int n_in,
                              void* d_out, int out_size, void* d_ws, size_t ws_size,
                              hipStream_t stream)
{
    const float* c_real = (const float*)d_in[0];
    const float* c_imag = (const float*)d_in[1];
    float* out = (float*)d_out;
    const int n = in_sizes[0];  // 4096*4096
    const int block = 256;
    const int gridA = (n + block - 1) / block;

    unsigned char* ws = (unsigned char*)d_ws;
    const size_t avail = (ws_size > 4096) ? (ws_size - 4096) : 0;
    unsigned seg_cap = (unsigned)(avail / (64u * 20u));  // 20B/record, 64 segs

    if (seg_cap < 1024u) {  // ws too small for compaction: proven fallback
        mandel_mono<<<gridA, block, 0, stream>>>(c_real, c_imag, out, n);
        return;
    }

    zero_ctrs<<<1, 128, 0, stream>>>(ws);
    mandel_stage_a<<<gridA, block, 0, stream>>>(c_real, c_imag, out, ws,
                                                seg_cap, n);
    // Persistent consumer: 64 segs x 32 blocks = 2048 blocks = 8192 waves
    // (32 waves/CU), each wave pulls records from its segment's cursor.
    mandel_stage_b<<<64 * 32, block, 0, stream>>>(out, ws, seg_cap);
}

// Round 3
// 252.602 us; speedup vs baseline: 1.0964x; 1.0964x over previous
//
#include <hip/hip_runtime.h>

// Mandelbrot counts — R6-proven bit-exact arithmetic + compaction + wave-
// aggregated enqueue (R8) + strip-mined recursive compaction (R11).
//
// R10 post-mortem: per-chunk dynamic refill made stage B CURSOR-ATOMIC-bound:
// every wave did a returning atomicAdd on one of 64 addresses every ~216
// cycles -> ~20x over same-address RMW capacity (~1/40cyc) -> convoy, B got
// SLOWER (150->168us) despite 3x less arithmetic. Lesson: with uniform-random
// c (no lane coherence) the only cheap work-redistribution is the proven
// "fixed-trip + ONE wave-aggregated enqueue atomic per wave" pattern.
//
// R11: strip-mine the 240 remaining checks into fixed strips with
// re-compaction between them (recursive application of the stage-A trick):
//   A : checks 0..15   (16)  all pixels          -> q0  (~1.92M survive)
//   B1: checks 16..55  (40)  q0 -> q1            (~0.80M survive)
//   B2: checks 56..135 (80)  q1 -> q0-storage    (~0.53M survive)
//   B3: checks 136..255(120) finish, write out
// Issued B-work ~205M lane-iters vs R8's 461M (2.25x); escaper waste is a
// partial strip; in-set records run at full SIMD utilization; enqueue atomic
// rate per address ~1/140cyc (proven fine in stage A). Queues ping-pong
// (2 x seg_cap records); if ws too small for both, fall back to the proven
// R8 single-queue fixed-240 stage B; tiny ws -> monolithic fallback.
//
// Proven iter body (absmax=0 in R6..R10), pinned with inline asm:
//   zi2 = fl32(zi*zi); mag = fma(zr,zr,zi2)
//   nr  = fl32(fma(zr,zr,-zi2) + cr); zi' = fma(2*zr, zi, ci)
// Cardioid/bulb shortcut margin 1e-3 (HW-validated, absmax=0).
//
// d_ws layout: [0,4096): 64 lines x 64B; line s dwords: +0 = A-enq (q0),
// +4 = B1-enq (q1), +8 = B2-enq (q0 reuse), +12 unused.
// q0: float4 recs @4096 (seg-major), int idx after; q1 after q0.
// Overflow at any enqueue -> finish inline (correct, slower). Queue order is
// nondeterministic but per-pixel values are deterministic.

#define MAX_ITERS 256

__device__ __forceinline__ float mul32(float a, float b) {
    float d; asm("v_mul_f32 %0, %1, %2" : "=v"(d) : "v"(a), "v"(b)); return d;
}
__device__ __forceinline__ float add32(float a, float b) {
    float d; asm("v_add_f32 %0, %1, %2" : "=v"(d) : "v"(a), "v"(b)); return d;
}
__device__ __forceinline__ float fma32(float a, float b, float c) {
    float d; asm("v_fma_f32 %0, %1, %2, %3" : "=v"(d) : "v"(a), "v"(b), "v"(c)); return d;
}
__device__ __forceinline__ float fma32_negc(float a, float b, float c) {
    float d; asm("v_fma_f32 %0, %1, %2, -%3" : "=v"(d) : "v"(a), "v"(b), "v"(c)); return d;
}

__device__ __forceinline__ void iter_checks(float cr, float ci,
                                            float& zr, float& zi,
                                            float& act, float& cnt, int nchecks)
{
    #pragma unroll 8
    for (int s = 0; s < nchecks; ++s) {
        const float zi2 = mul32(zi, zi);
        const float mag = fma32(zr, zr, zi2);
        act = (mag < 4.0f) ? act : 0.0f;      // sticky escape, NaN-safe
        cnt = cnt + act;                      // exact small-int add
        const float t   = fma32_negc(zr, zr, zi2);
        const float nr  = add32(t, cr);
        const float t2  = add32(zr, zr);
        zi = fma32(t2, zi, ci);
        zr = nr;
    }
}

__device__ __forceinline__ int lane_id() {
    return __builtin_amdgcn_mbcnt_hi(~0u, __builtin_amdgcn_mbcnt_lo(~0u, 0));
}

__global__ void zero_ctrs(unsigned char* ws) {
    // zero dwords +0,+4,+8,+12 of each of the 64 counter lines
    if (threadIdx.x < 256)
        *(unsigned*)(ws + (size_t)(threadIdx.x >> 2) * 64u
                        + (size_t)(threadIdx.x & 3) * 4u) = 0u;
}

__global__ __launch_bounds__(256) void mandel_stage_a(
    const float* __restrict__ c_real, const float* __restrict__ c_imag,
    float* __restrict__ out, unsigned char* __restrict__ ws,
    unsigned seg_cap, int n)
{
    int i = blockIdx.x * blockDim.x + threadIdx.x;
    if (i >= n) return;
    const float cr = c_real[i];
    const float ci = c_imag[i];

    // Closed-form safe-interior shortcut (margin absorbs any rounding).
    const float xq = cr - 0.25f;
    const float q  = xq * xq + ci * ci;
    const bool in_card = (q * (q + xq) - 0.25f * ci * ci) < -1e-3f;
    const float xb = cr + 1.0f;
    const bool in_bulb = (xb * xb + ci * ci) < (0.0625f - 1e-3f);
    const bool shortcut = in_card | in_bulb;

    float zr = cr, zi = ci, act = 1.0f, cnt = 0.0f;
    iter_checks(cr, ci, zr, zi, act, cnt, 16);   // checks z_0..z_15

    const bool surv = (!shortcut) && (act != 0.0f);

    // Wave-aggregated enqueue: one atomic per wave, striped over 64 counters.
    const unsigned long long m = __ballot(surv);
    if (m != 0ull) {
        const int lane = lane_id();
        const int leader = (int)__ffsll((unsigned long long)m) - 1;
        const int seg = blockIdx.x & 63;
        unsigned* ctr = (unsigned*)(ws + (size_t)seg * 64u);
        unsigned base = 0u;
        if (lane == leader) base = atomicAdd(ctr, (unsigned)__popcll(m));
        base = (unsigned)__shfl((int)base, leader, 64);
        if (surv) {
            const unsigned rank = (unsigned)__popcll(m & ((1ull << lane) - 1ull));
            const unsigned slot = base + rank;
            if (slot < seg_cap) {
                float4* q1f = (float4*)(ws + 4096);
                int*    q1i = (int*)(ws + 4096 + (size_t)seg_cap * 64u * 16u);
                const size_t p = (size_t)seg * seg_cap + slot;
                q1f[p] = make_float4(zr, zi, cr, ci);
                q1i[p] = i;
                return;
            }
            iter_checks(cr, ci, zr, zi, act, cnt, 240);  // overflow: inline
            out[i] = cnt;
            return;
        }
    }
    out[i] = shortcut ? 256.0f : cnt;
}

// Strip stage: fixed NCHECKS per record (checks START..START+NCHECKS-1).
// Survivors re-enqueued to dst via one wave-aggregated atomic per wave
// (HAS_DST) or finished (out=cnt, which is 256 for full survivors).
template <int NCHECKS, int START, bool HAS_DST>
__global__ __launch_bounds__(256) void mandel_strip(
    float* __restrict__ out, unsigned char* __restrict__ ws,
    const float4* __restrict__ srcF, const int* __restrict__ srcI,
    float4* __restrict__ dstF, int* __restrict__ dstI,
    int src_ctr, int dst_ctr, unsigned seg_cap, int blocks_per_seg)
{
    const int seg = (int)(blockIdx.x & 63u);
    const int grp = (int)(blockIdx.x >> 6);
    const unsigned cnt_s = *(const unsigned*)(ws + (size_t)seg * 64u
                                                 + (size_t)src_ctr * 4u);
    const unsigned nq = (cnt_s < seg_cap) ? cnt_s : seg_cap;
    const unsigned stride = (unsigned)blocks_per_seg * 256u;
    const int lane = lane_id();

    for (unsigned j = (unsigned)grp * 256u + threadIdx.x; j < nq; j += stride) {
        const size_t p = (size_t)seg * seg_cap + j;
        const float4 rec = srcF[p];
        const int idx = srcI[p];
        float zr = rec.x, zi = rec.y;
        const float cr = rec.z, ci = rec.w;
        float act = 1.0f, cnt = (float)START;
        iter_checks(cr, ci, zr, zi, act, cnt, NCHECKS);

        if (HAS_DST) {
            const bool surv = (act != 0.0f);
            const unsigned long long m = __ballot(surv);
            if (m != 0ull) {
                const int leader = (int)__ffsll((unsigned long long)m) - 1;
                unsigned* ctr = (unsigned*)(ws + (size_t)seg * 64u
                                               + (size_t)dst_ctr * 4u);
                unsigned base = 0u;
                if (lane == leader) base = atomicAdd(ctr, (unsigned)__popcll(m));
                base = (unsigned)__shfl((int)base, leader, 64);
                if (surv) {
                    const unsigned rank =
                        (unsigned)__popcll(m & ((1ull << lane) - 1ull));
                    const unsigned slot = base + rank;
                    if (slot < seg_cap) {
                        const size_t sp = (size_t)seg * seg_cap + slot;
                        dstF[sp] = make_float4(zr, zi, cr, ci);
                        dstI[sp] = idx;
                        continue;
                    }
                    // dst overflow: finish inline (correct, slower)
                    iter_checks(cr, ci, zr, zi, act, cnt,
                                256 - START - NCHECKS);
                    out[idx] = cnt;
                    continue;
                }
            }
            out[idx] = cnt;          // escaped during this strip
        } else {
            out[idx] = cnt;          // final strip: 256 if still active
        }
    }
}

// R8-proven fixed-240 stage B (fallback when ws can't hold two queues).
__global__ __launch_bounds__(256) void mandel_stage_b_fixed(
    float* __restrict__ out, const unsigned char* __restrict__ ws,
    unsigned seg_cap, int blocks_per_seg)
{
    const int seg = (int)(blockIdx.x & 63u);
    const int grp = (int)(blockIdx.x >> 6);
    const unsigned cnt_s = *(const unsigned*)(ws + (size_t)seg * 64u);
    const unsigned nq = (cnt_s < seg_cap) ? cnt_s : seg_cap;
    const float4* q1f = (const float4*)(ws + 4096);
    const int*    q1i = (const int*)(ws + 4096 + (size_t)seg_cap * 64u * 16u);
    const unsigned stride = (unsigned)blocks_per_seg * 256u;
    for (unsigned j = (unsigned)grp * 256u + threadIdx.x; j < nq; j += stride) {
        const size_t p = (size_t)seg * seg_cap + j;
        const float4 rec = q1f[p];
        const int idx = q1i[p];
        float zr = rec.x, zi = rec.y;
        const float cr = rec.z, ci = rec.w;
        float act = 1.0f, cnt = 16.0f;
        iter_checks(cr, ci, zr, zi, act, cnt, 240);  // checks z_16..z_255
        out[idx] = cnt;
    }
}

// Fallback: the R6-proven monolithic kernel (used only if d_ws is tiny).
__global__ __launch_bounds__(256) void mandel_mono(
    const float* __restrict__ c_real, const float* __restrict__ c_imag,
    float* __restrict__ out, int n)
{
    int i = blockIdx.x * blockDim.x + threadIdx.x;
    if (i >= n) return;
    const float cr = c_real[i], ci = c_imag[i];
    float zr = cr, zi = ci, act = 1.0f, cnt = 0.0f;
    iter_checks(cr, ci, zr, zi, act, cnt, MAX_ITERS);
    out[i] = cnt;
}

extern "C" void kernel_launch(void* const* d_in, const int* in_sizes, int n_in,
                              void* d_out, int out_size, void* d_ws, size_t ws_size,
                              hipStream_t stream)
{
    const float* c_real = (const float*)d_in[0];
    const float* c_imag = (const float*)d_in[1];
    float* out = (float*)d_out;
    const int n = in_sizes[0];  // 4096*4096
    const int block = 256;
    const int gridA = (n + block - 1) / block;

    unsigned char* ws = (unsigned char*)d_ws;
    const size_t avail = (ws_size > 4096) ? (ws_size - 4096) : 0;
    const unsigned seg_cap1 = (unsigned)(avail / (64u * 20u));        // 1 queue
    const unsigned seg_cap2 = (unsigned)(avail / (64u * 20u * 2u));   // 2 queues

    if (seg_cap1 < 1024u) {  // ws too small for compaction: proven fallback
        mandel_mono<<<gridA, block, 0, stream>>>(c_real, c_imag, out, n);
        return;
    }

    zero_ctrs<<<1, 256, 0, stream>>>(ws);

    if (seg_cap2 >= 33000u) {
        // Strip-mined ladder with ping-pong queues (need ~30k recs/seg in q0).
        const unsigned sc = seg_cap2;
        float4* q0f = (float4*)(ws + 4096);
        int*    q0i = (int*)(ws + 4096 + (size_t)sc * 64u * 16u);
        float4* q1f = (float4*)(ws + 4096 + (size_t)sc * 64u * 20u);
        int*    q1i = (int*)(ws + 4096 + (size_t)sc * 64u * 20u
                                       + (size_t)sc * 64u * 16u);

        mandel_stage_a<<<gridA, block, 0, stream>>>(c_real, c_imag, out, ws,
                                                    sc, n);
        // B1: checks 16..55 (40), q0 -> q1 (ctr 0 -> ctr 1)
        mandel_strip<40, 16, true><<<64 * 128, block, 0, stream>>>(
            out, ws, q0f, q0i, q1f, q1i, 0, 1, sc, 128);
        // B2: checks 56..135 (80), q1 -> q0 storage (ctr 1 -> ctr 2)
        mandel_strip<80, 56, true><<<64 * 64, block, 0, stream>>>(
            out, ws, q1f, q1i, q0f, q0i, 1, 2, sc, 64);
        // B3: checks 136..255 (120), finish (ctr 2)
        mandel_strip<120, 136, false><<<64 * 64, block, 0, stream>>>(
            out, ws, q0f, q0i, (float4*)nullptr, (int*)nullptr, 2, 0, sc, 64);
        return;
    }

    // R8-proven two-stage path (single queue, fixed-240 stage B).
    mandel_stage_a<<<gridA, block, 0, stream>>>(c_real, c_imag, out, ws,
                                                seg_cap1, n);
    const int blocks_per_seg = 256;
    mandel_stage_b_fixed<<<64 * blocks_per_seg, block, 0, stream>>>(
        out, ws, seg_cap1, blocks_per_seg);
}

// Round 4
// 234.807 us; speedup vs baseline: 1.1795x; 1.0758x over previous
//
#include <hip/hip_runtime.h>

// Mandelbrot counts — R6-proven bit-exact arithmetic + compaction + wave-
// aggregated enqueue (R8) + strip-mined recursive compaction (R11) +
// PACKED-FP32 2-pixels-per-lane arithmetic (R12).
//
// R11 post-mortem: stage A 110us @ VALUBusy 76%, HBM 19% — VALU-ISSUE bound.
// Useful work ~170 instrs/px -> ~36us at full issue; the 3x gap is per-check
// issue fat (9 scalar VALU + asm-block movs, every op a full wave64 slot).
// R12: gfx950 has full-rate packed fp32 (v_pk_{fma,mul,add}_f32, same
// IEEE rounding per half as the scalar ops). Two pixels per lane:
//   per check/2px: 7 pk + 2 v_xor (exact -zi2 signflip) + 2 cmp + 2 cndmask
//   = 13 slots vs ~18-25 scalar -> ~2x issue reduction on A and all strips.
// Enqueue stays the proven ONE-atomic-per-wave pattern, balloting two
// survivor masks (m0,m1), one atomicAdd of popc(m0)+popc(m1).
// Strips pair record k with k+ceil(nq/2) so loads stay coalesced.
//
// Exactness: each pk component applies the exact proven sequence
//   zi2 = fl(zi*zi); mag = fma(zr,zr,zi2)
//   t = fma(zr,zr,-zi2) [sign-bit flip of zi2, == HW neg modifier]
//   nr = fl(t + cr); t2 = fl(zr+zr); zi' = fma(t2, zi, ci)
//   act = (mag<4) ? act : 0 (sticky, NaN-safe); cnt = fl(cnt+act)
// identical to the absmax=0 lineage (R6..R11). Cardioid/bulb shortcut
// margin 1e-3 (HW-validated).
//
// Ladder: A: checks 0..15 (all px) -> q0 | B1: 16..55 q0->q1 |
// B2: 56..135 q1->q0 | B3: 136..255 finish. Counters: line dwords +0/+4/+8.
// Overflow at any enqueue -> finish inline (correct, slower). ws too small
// for 2 queues -> proven R8 scalar path; tiny ws -> monolithic fallback.

#define MAX_ITERS 256

typedef __attribute__((ext_vector_type(2))) float f32x2;

// ---------- scalar proven body (fallback paths + overflow inline) ----------
__device__ __forceinline__ float mul32(float a, float b) {
    float d; asm("v_mul_f32 %0, %1, %2" : "=v"(d) : "v"(a), "v"(b)); return d;
}
__device__ __forceinline__ float add32(float a, float b) {
    float d; asm("v_add_f32 %0, %1, %2" : "=v"(d) : "v"(a), "v"(b)); return d;
}
__device__ __forceinline__ float fma32(float a, float b, float c) {
    float d; asm("v_fma_f32 %0, %1, %2, %3" : "=v"(d) : "v"(a), "v"(b), "v"(c)); return d;
}
__device__ __forceinline__ float fma32_negc(float a, float b, float c) {
    float d; asm("v_fma_f32 %0, %1, %2, -%3" : "=v"(d) : "v"(a), "v"(b), "v"(c)); return d;
}

__device__ __forceinline__ void iter_checks(float cr, float ci,
                                            float& zr, float& zi,
                                            float& act, float& cnt, int nchecks)
{
    #pragma unroll 8
    for (int s = 0; s < nchecks; ++s) {
        const float zi2 = mul32(zi, zi);
        const float mag = fma32(zr, zr, zi2);
        act = (mag < 4.0f) ? act : 0.0f;
        cnt = cnt + act;
        const float t   = fma32_negc(zr, zr, zi2);
        const float nr  = add32(t, cr);
        const float t2  = add32(zr, zr);
        zi = fma32(t2, zi, ci);
        zr = nr;
    }
}

// ---------- packed (2 px/lane) body ----------
__device__ __forceinline__ f32x2 pk_mul(f32x2 a, f32x2 b) {
    f32x2 d; asm("v_pk_mul_f32 %0, %1, %2" : "=v"(d) : "v"(a), "v"(b)); return d;
}
__device__ __forceinline__ f32x2 pk_add(f32x2 a, f32x2 b) {
    f32x2 d; asm("v_pk_add_f32 %0, %1, %2" : "=v"(d) : "v"(a), "v"(b)); return d;
}
__device__ __forceinline__ f32x2 pk_fma(f32x2 a, f32x2 b, f32x2 c) {
    f32x2 d; asm("v_pk_fma_f32 %0, %1, %2, %3" : "=v"(d) : "v"(a), "v"(b), "v"(c)); return d;
}

__device__ __forceinline__ void iter_checks_pk(const f32x2 cr, const f32x2 ci,
                                               f32x2& zr, f32x2& zi,
                                               f32x2& act, f32x2& cnt,
                                               int nchecks)
{
    #pragma unroll 8
    for (int s = 0; s < nchecks; ++s) {
        const f32x2 zi2  = pk_mul(zi, zi);
        const f32x2 mag  = pk_fma(zr, zr, zi2);
        const f32x2 mzi2 = -zi2;                 // sign-bit flip, exact
        const f32x2 t    = pk_fma(zr, zr, mzi2);
        const f32x2 nr   = pk_add(t, cr);
        const f32x2 t2   = pk_add(zr, zr);
        const f32x2 nzi  = pk_fma(t2, zi, ci);
        act.x = (mag.x < 4.0f) ? act.x : 0.0f;   // sticky escape, NaN-safe
        act.y = (mag.y < 4.0f) ? act.y : 0.0f;
        cnt = pk_add(cnt, act);                  // exact small-int add
        zr = nr; zi = nzi;
    }
}

__device__ __forceinline__ int lane_id() {
    return __builtin_amdgcn_mbcnt_hi(~0u, __builtin_amdgcn_mbcnt_lo(~0u, 0));
}

__device__ __forceinline__ bool in_shortcut(float cr, float ci) {
    const float xq = cr - 0.25f;
    const float q  = xq * xq + ci * ci;
    const bool in_card = (q * (q + xq) - 0.25f * ci * ci) < -1e-3f;
    const float xb = cr + 1.0f;
    const bool in_bulb = (xb * xb + ci * ci) < (0.0625f - 1e-3f);
    return in_card | in_bulb;
}

__global__ void zero_ctrs(unsigned char* ws) {
    if (threadIdx.x < 256)
        *(unsigned*)(ws + (size_t)(threadIdx.x >> 2) * 64u
                        + (size_t)(threadIdx.x & 3) * 4u) = 0u;
}

// ---------- stage A, packed: 2 pixels per thread ----------
__global__ __launch_bounds__(256) void mandel_stage_a_pk(
    const float* __restrict__ c_real, const float* __restrict__ c_imag,
    float* __restrict__ out, unsigned char* __restrict__ ws,
    unsigned seg_cap, int n)
{
    const int tp = blockIdx.x * blockDim.x + threadIdx.x;
    const int p0 = tp << 1;
    if (p0 >= n) return;
    const bool has1 = (p0 + 1) < n;

    f32x2 cr, ci;
    if (has1) {
        cr = *(const f32x2*)(c_real + p0);
        ci = *(const f32x2*)(c_imag + p0);
    } else {
        cr.x = c_real[p0]; cr.y = 0.0f;
        ci.x = c_imag[p0]; ci.y = 0.0f;
    }
    const bool sc0 = in_shortcut(cr.x, ci.x);
    const bool sc1 = in_shortcut(cr.y, ci.y);

    f32x2 zr = cr, zi = ci;
    f32x2 act; act.x = 1.0f; act.y = has1 ? 1.0f : 0.0f;
    f32x2 cnt = {0.0f, 0.0f};
    iter_checks_pk(cr, ci, zr, zi, act, cnt, 16);   // checks z_0..z_15

    const bool s0 = (!sc0) && (act.x != 0.0f);
    const bool s1 = has1 && (!sc1) && (act.y != 0.0f);

    const unsigned long long m0 = __ballot(s0);
    const unsigned long long m1 = __ballot(s1);
    if ((m0 | m1) != 0ull) {
        const int lane = lane_id();
        const int leader = (int)__ffsll(m0 | m1) - 1;
        const int seg = blockIdx.x & 63;
        unsigned* ctr = (unsigned*)(ws + (size_t)seg * 64u);
        unsigned base = 0u;
        if (lane == leader)
            base = atomicAdd(ctr, (unsigned)(__popcll(m0) + __popcll(m1)));
        base = (unsigned)__shfl((int)base, leader, 64);
        float4* qf = (float4*)(ws + 4096);
        int*    qi = (int*)(ws + 4096 + (size_t)seg_cap * 64u * 16u);
        if (s0) {
            const unsigned slot = base +
                (unsigned)__popcll(m0 & ((1ull << lane) - 1ull));
            if (slot < seg_cap) {
                const size_t p = (size_t)seg * seg_cap + slot;
                qf[p] = make_float4(zr.x, zi.x, cr.x, ci.x);
                qi[p] = p0;
            } else {
                float zrs = zr.x, zis = zi.x, as = 1.0f, cs = cnt.x;
                iter_checks(cr.x, ci.x, zrs, zis, as, cs, 240);
                out[p0] = cs;
            }
        }
        if (s1) {
            const unsigned slot = base + (unsigned)__popcll(m0) +
                (unsigned)__popcll(m1 & ((1ull << lane) - 1ull));
            if (slot < seg_cap) {
                const size_t p = (size_t)seg * seg_cap + slot;
                qf[p] = make_float4(zr.y, zi.y, cr.y, ci.y);
                qi[p] = p0 + 1;
            } else {
                float zrs = zr.y, zis = zi.y, as = 1.0f, cs = cnt.y;
                iter_checks(cr.y, ci.y, zrs, zis, as, cs, 240);
                out[p0 + 1] = cs;
            }
        }
    }
    if (!s0) out[p0] = sc0 ? 256.0f : cnt.x;
    if (has1 && !s1) out[p0 + 1] = sc1 ? 256.0f : cnt.y;
}

// ---------- strip stage, packed: 2 records per thread ----------
// Pairs record k with k + ceil(nq/2) so both float4 loads stay coalesced.
template <int NCHECKS, int START, bool HAS_DST>
__global__ __launch_bounds__(256) void mandel_strip_pk(
    float* __restrict__ out, unsigned char* __restrict__ ws,
    const float4* __restrict__ srcF, const int* __restrict__ srcI,
    float4* __restrict__ dstF, int* __restrict__ dstI,
    int src_ctr, int dst_ctr, unsigned seg_cap, int blocks_per_seg)
{
    const int seg = (int)(blockIdx.x & 63u);
    const int grp = (int)(blockIdx.x >> 6);
    const unsigned cnt_s = *(const unsigned*)(ws + (size_t)seg * 64u
                                                 + (size_t)src_ctr * 4u);
    const unsigned nq = (cnt_s < seg_cap) ? cnt_s : seg_cap;
    const unsigned half = (nq + 1u) >> 1;
    const unsigned stride = (unsigned)blocks_per_seg * 256u;
    const int lane = lane_id();
    const size_t segbase = (size_t)seg * seg_cap;

    for (unsigned k = (unsigned)grp * 256u + threadIdx.x; k < half; k += stride) {
        const unsigned r1 = k + half;
        const bool v1 = (r1 < nq);
        const float4 rec0 = srcF[segbase + k];
        const float4 rec1 = v1 ? srcF[segbase + r1] : rec0;
        const int idx0 = srcI[segbase + k];
        const int idx1 = v1 ? srcI[segbase + r1] : -1;
        f32x2 zr; zr.x = rec0.x; zr.y = rec1.x;
        f32x2 zi; zi.x = rec0.y; zi.y = rec1.y;
        f32x2 cr; cr.x = rec0.z; cr.y = rec1.z;
        f32x2 ci; ci.x = rec0.w; ci.y = rec1.w;
        f32x2 act; act.x = 1.0f; act.y = v1 ? 1.0f : 0.0f;
        f32x2 cnt = {(float)START, (float)START};
        iter_checks_pk(cr, ci, zr, zi, act, cnt, NCHECKS);
        const bool s0 = (act.x != 0.0f);
        const bool s1 = (act.y != 0.0f);    // invalid half: act.y==0 always

        if (HAS_DST) {
            const unsigned long long m0 = __ballot(s0);
            const unsigned long long m1 = __ballot(s1);
            if ((m0 | m1) != 0ull) {
                const int leader = (int)__ffsll(m0 | m1) - 1;
                unsigned* ctr = (unsigned*)(ws + (size_t)seg * 64u
                                               + (size_t)dst_ctr * 4u);
                unsigned base = 0u;
                if (lane == leader)
                    base = atomicAdd(ctr,
                        (unsigned)(__popcll(m0) + __popcll(m1)));
                base = (unsigned)__shfl((int)base, leader, 64);
                if (s0) {
                    const unsigned slot = base +
                        (unsigned)__popcll(m0 & ((1ull << lane) - 1ull));
                    if (slot < seg_cap) {
                        const size_t sp = segbase + slot;
                        dstF[sp] = make_float4(zr.x, zi.x, cr.x, ci.x);
                        dstI[sp] = idx0;
                    } else {
                        float zrs = zr.x, zis = zi.x, as = 1.0f, cs = cnt.x;
                        iter_checks(cr.x, ci.x, zrs, zis, as, cs,
                                    256 - START - NCHECKS);
                        out[idx0] = cs;
                    }
                }
                if (s1) {
                    const unsigned slot = base + (unsigned)__popcll(m0) +
                        (unsigned)__popcll(m1 & ((1ull << lane) - 1ull));
                    if (slot < seg_cap) {
                        const size_t sp = segbase + slot;
                        dstF[sp] = make_float4(zr.y, zi.y, cr.y, ci.y);
                        dstI[sp] = idx1;
                    } else {
                        float zrs = zr.y, zis = zi.y, as = 1.0f, cs = cnt.y;
                        iter_checks(cr.y, ci.y, zrs, zis, as, cs,
                                    256 - START - NCHECKS);
                        out[idx1] = cs;
                    }
                }
            }
            if (!s0) out[idx0] = cnt.x;          // escaped this strip
            if (v1 && !s1) out[idx1] = cnt.y;
        } else {
            out[idx0] = cnt.x;                   // final strip
            if (v1) out[idx1] = cnt.y;
        }
    }
}

// ---------- proven scalar fallbacks ----------
__global__ __launch_bounds__(256) void mandel_stage_a(
    const float* __restrict__ c_real, const float* __restrict__ c_imag,
    float* __restrict__ out, unsigned char* __restrict__ ws,
    unsigned seg_cap, int n)
{
    int i = blockIdx.x * blockDim.x + threadIdx.x;
    if (i >= n) return;
    const float cr = c_real[i];
    const float ci = c_imag[i];
    const bool shortcut = in_shortcut(cr, ci);

    float zr = cr, zi = ci, act = 1.0f, cnt = 0.0f;
    iter_checks(cr, ci, zr, zi, act, cnt, 16);

    const bool surv = (!shortcut) && (act != 0.0f);
    const unsigned long long m = __ballot(surv);
    if (m != 0ull) {
        const int lane = lane_id();
        const int leader = (int)__ffsll((unsigned long long)m) - 1;
        const int seg = blockIdx.x & 63;
        unsigned* ctr = (unsigned*)(ws + (size_t)seg * 64u);
        unsigned base = 0u;
        if (lane == leader) base = atomicAdd(ctr, (unsigned)__popcll(m));
        base = (unsigned)__shfl((int)base, leader, 64);
        if (surv) {
            const unsigned rank = (unsigned)__popcll(m & ((1ull << lane) - 1ull));
            const unsigned slot = base + rank;
            if (slot < seg_cap) {
                float4* q1f = (float4*)(ws + 4096);
                int*    q1i = (int*)(ws + 4096 + (size_t)seg_cap * 64u * 16u);
                const size_t p = (size_t)seg * seg_cap + slot;
                q1f[p] = make_float4(zr, zi, cr, ci);
                q1i[p] = i;
                return;
            }
            iter_checks(cr, ci, zr, zi, act, cnt, 240);
            out[i] = cnt;
            return;
        }
    }
    out[i] = shortcut ? 256.0f : cnt;
}

__global__ __launch_bounds__(256) void mandel_stage_b_fixed(
    float* __restrict__ out, const unsigned char* __restrict__ ws,
    unsigned seg_cap, int blocks_per_seg)
{
    const int seg = (int)(blockIdx.x & 63u);
    const int grp = (int)(blockIdx.x >> 6);
    const unsigned cnt_s = *(const unsigned*)(ws + (size_t)seg * 64u);
    const unsigned nq = (cnt_s < seg_cap) ? cnt_s : seg_cap;
    const float4* q1f = (const float4*)(ws + 4096);
    const int*    q1i = (const int*)(ws + 4096 + (size_t)seg_cap * 64u * 16u);
    const unsigned stride = (unsigned)blocks_per_seg * 256u;
    for (unsigned j = (unsigned)grp * 256u + threadIdx.x; j < nq; j += stride) {
        const size_t p = (size_t)seg * seg_cap + j;
        const float4 rec = q1f[p];
        const int idx = q1i[p];
        float zr = rec.x, zi = rec.y;
        const float cr = rec.z, ci = rec.w;
        float act = 1.0f, cnt = 16.0f;
        iter_checks(cr, ci, zr, zi, act, cnt, 240);
        out[idx] = cnt;
    }
}

__global__ __launch_bounds__(256) void mandel_mono(
    const float* __restrict__ c_real, const float* __restrict__ c_imag,
    float* __restrict__ out, int n)
{
    int i = blockIdx.x * blockDim.x + threadIdx.x;
    if (i >= n) return;
    const float cr = c_real[i], ci = c_imag[i];
    float zr = cr, zi = ci, act = 1.0f, cnt = 0.0f;
    iter_checks(cr, ci, zr, zi, act, cnt, MAX_ITERS);
    out[i] = cnt;
}

extern "C" void kernel_launch(void* const* d_in, const int* in_sizes, int n_in,
                              void* d_out, int out_size, void* d_ws, size_t ws_size,
                              hipStream_t stream)
{
    const float* c_real = (const float*)d_in[0];
    const float* c_imag = (const float*)d_in[1];
    float* out = (float*)d_out;
    const int n = in_sizes[0];  // 4096*4096
    const int block = 256;

    unsigned char* ws = (unsigned char*)d_ws;
    const size_t avail = (ws_size > 4096) ? (ws_size - 4096) : 0;
    const unsigned seg_cap1 = (unsigned)(avail / (64u * 20u));        // 1 queue
    const unsigned seg_cap2 = (unsigned)(avail / (64u * 20u * 2u));   // 2 queues

    if (seg_cap1 < 1024u) {  // ws too small for compaction: proven fallback
        const int gridA = (n + block - 1) / block;
        mandel_mono<<<gridA, block, 0, stream>>>(c_real, c_imag, out, n);
        return;
    }

    zero_ctrs<<<1, 256, 0, stream>>>(ws);

    if (seg_cap2 >= 33000u) {
        // Packed strip-mined ladder with ping-pong queues.
        const unsigned sc = seg_cap2;
        float4* q0f = (float4*)(ws + 4096);
        int*    q0i = (int*)(ws + 4096 + (size_t)sc * 64u * 16u);
        float4* q1f = (float4*)(ws + 4096 + (size_t)sc * 64u * 20u);
        int*    q1i = (int*)(ws + 4096 + (size_t)sc * 64u * 20u
                                       + (size_t)sc * 64u * 16u);

        const int npairs = (n + 1) / 2;
        const int gridA = (npairs + block - 1) / block;
        mandel_stage_a_pk<<<gridA, block, 0, stream>>>(c_real, c_imag, out,
                                                       ws, sc, n);
        // B1: checks 16..55 (40), q0 -> q1 (ctr 0 -> ctr 1)
        mandel_strip_pk<40, 16, true><<<64 * 64, block, 0, stream>>>(
            out, ws, q0f, q0i, q1f, q1i, 0, 1, sc, 64);
        // B2: checks 56..135 (80), q1 -> q0 storage (ctr 1 -> ctr 2)
        mandel_strip_pk<80, 56, true><<<64 * 32, block, 0, stream>>>(
            out, ws, q1f, q1i, q0f, q0i, 1, 2, sc, 32);
        // B3: checks 136..255 (120), finish (ctr 2)
        mandel_strip_pk<120, 136, false><<<64 * 32, block, 0, stream>>>(
            out, ws, q0f, q0i, (float4*)nullptr, (int*)nullptr, 2, 0, sc, 32);
        return;
    }

    // R8-proven two-stage scalar path (single queue, fixed-240 stage B).
    const int gridA = (n + block - 1) / block;
    mandel_stage_a<<<gridA, block, 0, stream>>>(c_real, c_imag, out, ws,
                                                seg_cap1, n);
    const int blocks_per_seg = 256;
    mandel_stage_b_fixed<<<64 * blocks_per_seg, block, 0, stream>>>(
        out, ws, seg_cap1, blocks_per_seg);
}